// Round 5
// baseline (769.646 us; speedup 1.0000x reference)
//
#include <hip/hip_runtime.h>
#include <hip/hip_fp16.h>
#include <math.h>

#define N_NODES 100000
#define N_EDGES 1600000
#define F_IN 15
#define NB_NODES 391   // ceil(N_NODES/256)
#define MASK40 ((1ull << 40) - 1)

// ---------------- prelude ----------------

__global__ void k_initp(unsigned long long* __restrict__ packed) {
    int i = blockIdx.x * blockDim.x + threadIdx.x;
    if (i < N_NODES) packed[i] = 0ull;
}

// one packed 64-bit atomic per edge: count in bits [40..], weight-sum as 32.8
// fixed point in bits [0..40). Returned old count = this edge's CSR ordinal.
// (R4 learning: atomic cost ~ transaction count, not payload width — keep 1 op.)
__global__ void k_cnt(const int* __restrict__ dst, const float* __restrict__ w,
                      unsigned long long* __restrict__ packed, int* __restrict__ ord) {
    int i = blockIdx.x * blockDim.x + threadIdx.x;
    if (i >= N_EDGES) return;
    int d = dst[i];
    unsigned long long contrib =
        (1ull << 40) + (unsigned long long)((double)w[i] * 4294967296.0);
    unsigned long long old = atomicAdd(&packed[d], contrib);
    ord[i] = (int)(old >> 40);
}

// per-block sum of counts -> bsum; fused dinv = rsqrt(1 + sum_w)
__global__ void k_part(const unsigned long long* __restrict__ packed,
                       int* __restrict__ bsum, float* __restrict__ dinv) {
    __shared__ int red[256];
    int t = threadIdx.x;
    int i = blockIdx.x * 256 + t;
    int c = 0;
    if (i < N_NODES) {
        unsigned long long p = packed[i];
        c = (int)(p >> 40);
        float deg = 1.0f + (float)((double)(p & MASK40) * 0x1p-32);  // + self loop
        dinv[i] = rsqrtf(deg);
    }
    red[t] = c;
    __syncthreads();
    for (int off = 128; off > 0; off >>= 1) {
        if (t < off) red[t] += red[t + off];
        __syncthreads();
    }
    if (t == 0) bsum[blockIdx.x] = red[0];
}

// single-block exclusive scan of bsum[NB_NODES]
__global__ __launch_bounds__(512) void k_scanb(int* __restrict__ bsum,
                                               int* __restrict__ rowptr) {
    __shared__ int sc[512];
    int t = threadIdx.x;
    int v = (t < NB_NODES) ? bsum[t] : 0;
    sc[t] = v;
    __syncthreads();
    for (int off = 1; off < 512; off <<= 1) {
        int u = (t >= off) ? sc[t - off] : 0;
        __syncthreads();
        sc[t] += u;
        __syncthreads();
    }
    if (t < NB_NODES) bsum[t] = sc[t] - v;  // exclusive
    if (t == 0) rowptr[N_NODES] = N_EDGES;  // total is a compile-time constant
}

// in-block exclusive scan of counts + block offset -> rowptr
__global__ void k_fillptr(const unsigned long long* __restrict__ packed,
                          const int* __restrict__ bsum, int* __restrict__ rowptr) {
    __shared__ int sc[256];
    int t = threadIdx.x;
    int i = blockIdx.x * 256 + t;
    int v = (i < N_NODES) ? (int)(packed[i] >> 40) : 0;
    sc[t] = v;
    __syncthreads();
    for (int off = 1; off < 256; off <<= 1) {
        int u = (t >= off) ? sc[t - off] : 0;
        __syncthreads();
        sc[t] += u;
        __syncthreads();
    }
    if (i < N_NODES) rowptr[i] = bsum[blockIdx.x] + sc[t] - v;
}

// atomic-free CSR fill: slot = rowptr[dst] + per-edge ordinal
__global__ void k_fill(const int* __restrict__ src, const int* __restrict__ dst,
                       const float* __restrict__ w, const float* __restrict__ dinv,
                       const int* __restrict__ rowptr, const int* __restrict__ ord,
                       int2* __restrict__ csr) {
    int i = blockIdx.x * blockDim.x + threadIdx.x;
    if (i >= N_EDGES) return;
    int s = src[i], d = dst[i];
    float nm = dinv[s] * w[i] * dinv[d];
    csr[rowptr[d] + ord[i]] = make_int2(s, __float_as_int(nm));
}

// ---------------- layer 0 dense transform: [N,15]@[15,64] -> fp16 ----------------

__global__ void k_gemm0(const float* __restrict__ x, const float* __restrict__ W,
                        __half* __restrict__ out) {
    __shared__ float Ws[F_IN * 64];
    int t = threadIdx.x;
    for (int i = t; i < F_IN * 64; i += 256) Ws[i] = W[i];
    __syncthreads();
    int r = blockIdx.x * 4 + (t >> 6);
    int c = t & 63;
    if (r < N_NODES) {
        const float* xr = x + (long)r * F_IN;
        float acc = 0.f;
#pragma unroll
        for (int k = 0; k < F_IN; k++) acc += xr[k] * Ws[k * 64 + c];
        out[(long)r * 64 + c] = __float2half(acc);
    }
}

// ---------------- fused aggregation (+ optional dense epilogue) ----------------
// out = (A act(hin)) [W] + b.  One wave per node, processing 2 edges at a time:
// lane = (sub: which edge of the pair) x (fl: feature-pair, half2 load).
// 32 lanes x 4B = one 128B line per edge row; unroll 4 -> 8 rows in flight/wave.

template <bool RELU, bool WEP, bool SIG>
__global__ __launch_bounds__(256) void k_gather2(
        const int* __restrict__ rowptr, const int2* __restrict__ csr,
        const __half* __restrict__ hin, const float* __restrict__ dinv,
        const float* __restrict__ W, const float* __restrict__ b,
        void* __restrict__ outp) {
    __shared__ float Ws[64 * 64];
    __shared__ float gs[4 * 64];
    int t = threadIdx.x;
    if (WEP) {
        const float4* W4 = (const float4*)W;
        float4* Ws4 = (float4*)Ws;
        for (int i = t; i < 64 * 16; i += 256) Ws4[i] = W4[i];
        __syncthreads();
    }

    int wv = t >> 6, lane = t & 63;
    int sub = lane >> 5;   // which edge of the current pair
    int fl = lane & 31;    // feature-pair index (features 2fl, 2fl+1)
    float bl = b[lane];
    float* gw = gs + wv * 64;
    const __half2* h2 = (const __half2*)hin;  // row stride = 32 half2

#pragma unroll 1
    for (int j = 0; j < 8; j++) {
        int n = blockIdx.x * 32 + j * 4 + wv;  // grid sized so n < N_NODES always
        int e0 = __builtin_amdgcn_readfirstlane(rowptr[n]);
        int e1 = __builtin_amdgcn_readfirstlane(rowptr[n + 1]);
        float dv = dinv[n];

        // self-loop term on sub==0 half only
        float2 acc;
        {
            float2 hf = __half22float2(h2[(long)n * 32 + fl]);
            if (RELU) { hf.x = fmaxf(hf.x, 0.f); hf.y = fmaxf(hf.y, 0.f); }
            float w0 = (sub == 0) ? dv * dv : 0.f;
            acc.x = w0 * hf.x; acc.y = w0 * hf.y;
        }

        int e = e0 + sub;  // sub-halves take alternating edges
        for (; e + 6 < e1; e += 8) {
            int2 r0 = csr[e], r1 = csr[e + 2], r2 = csr[e + 4], r3 = csr[e + 6];
            float2 f0 = __half22float2(h2[(long)r0.x * 32 + fl]);
            float2 f1 = __half22float2(h2[(long)r1.x * 32 + fl]);
            float2 f2 = __half22float2(h2[(long)r2.x * 32 + fl]);
            float2 f3 = __half22float2(h2[(long)r3.x * 32 + fl]);
            if (RELU) {
                f0.x = fmaxf(f0.x, 0.f); f0.y = fmaxf(f0.y, 0.f);
                f1.x = fmaxf(f1.x, 0.f); f1.y = fmaxf(f1.y, 0.f);
                f2.x = fmaxf(f2.x, 0.f); f2.y = fmaxf(f2.y, 0.f);
                f3.x = fmaxf(f3.x, 0.f); f3.y = fmaxf(f3.y, 0.f);
            }
            float n0 = __int_as_float(r0.y), n1 = __int_as_float(r1.y);
            float n2 = __int_as_float(r2.y), n3 = __int_as_float(r3.y);
            acc.x += n0 * f0.x; acc.y += n0 * f0.y;
            acc.x += n1 * f1.x; acc.y += n1 * f1.y;
            acc.x += n2 * f2.x; acc.y += n2 * f2.y;
            acc.x += n3 * f3.x; acc.y += n3 * f3.y;
        }
        for (; e < e1; e += 2) {
            int2 r = csr[e];
            float2 f = __half22float2(h2[(long)r.x * 32 + fl]);
            if (RELU) { f.x = fmaxf(f.x, 0.f); f.y = fmaxf(f.y, 0.f); }
            float nm = __int_as_float(r.y);
            acc.x += nm * f.x; acc.y += nm * f.y;
        }

        // combine the two sub-halves (feature pair fl lives in lanes fl and fl+32)
        acc.x += __shfl_xor(acc.x, 32);
        acc.y += __shfl_xor(acc.y, 32);
        if (sub == 0) {
            gw[2 * fl] = acc.x;
            gw[2 * fl + 1] = acc.y;
        }
        __builtin_amdgcn_wave_barrier();

        float o;
        if (WEP) {
            o = bl;
#pragma unroll
            for (int k = 0; k < 64; k++) o += gw[k] * Ws[k * 64 + lane];
        } else {
            o = gw[lane] + bl;
        }
        if (SIG) {
            o = 1.0f / (1.0f + expf(-o));
            ((float*)outp)[(long)n * 64 + lane] = o;
        } else {
            ((__half*)outp)[(long)n * 64 + lane] = __float2half(o);  // pre-relu
        }
        __builtin_amdgcn_wave_barrier();
    }
}

// ---------------- launch ----------------

extern "C" void kernel_launch(void* const* d_in, const int* in_sizes, int n_in,
                              void* d_out, int out_size, void* d_ws, size_t ws_size,
                              hipStream_t stream) {
    const float* x  = (const float*)d_in[0];
    const int*   ei = (const int*)  d_in[1];
    const float* ew = (const float*)d_in[2];
    const float* W0 = (const float*)d_in[3];
    const float* b0 = (const float*)d_in[4];
    const float* Wm = (const float*)d_in[5];
    const float* bm = (const float*)d_in[6];
    const float* Wl = (const float*)d_in[7];
    const float* bl = (const float*)d_in[8];
    float* out = (float*)d_out;

    const int* src = ei;
    const int* dst = ei + N_EDGES;

    char* ws = (char*)d_ws;
    unsigned long long* packed = (unsigned long long*)(ws + 0);        // 800 KB
    float*  dinv   = (float*)(ws + (1u  << 20));                        // 400 KB
    int*    rowptr = (int*)  (ws + (2u  << 20));                        // 400 KB
    int*    bsum   = (int*)  (ws + (3u  << 20));                        // 2 KB
    int*    ord    = (int*)  (ws + (3u  << 20) + 65536);                // 6.4 MB
    int2*   csr    = (int2*) (ws + (11u << 20));                        // 12.8 MB
    __half* htmp   = (__half*)(ws + (24u << 20));                       // 12.8 MB
    __half* hA     = (__half*)(ws + (50u << 20));                       // 12.8 MB
    __half* hB     = (__half*)(ws + (63u << 20));                       // 12.8 MB

    const int BT = 256;
    dim3 blk(BT);
    int gN   = NB_NODES;                       // 391
    int gE   = (N_EDGES + BT - 1) / BT;        // 6250
    int gR4  = (N_NODES + 3) / 4;              // 25000 (gemm0)
    int gWF  = N_NODES / 32;                   // 3125 (gather2: 32 nodes/block, exact)

    // prelude: packed count+degree, 3-phase scan, atomic-free CSR fill
    hipLaunchKernelGGL(k_initp,   dim3(gN), blk, 0, stream, packed);
    hipLaunchKernelGGL(k_cnt,     dim3(gE), blk, 0, stream, dst, ew, packed, ord);
    hipLaunchKernelGGL(k_part,    dim3(gN), blk, 0, stream, packed, bsum, dinv);
    hipLaunchKernelGGL(k_scanb,   dim3(1), dim3(512), 0, stream, bsum, rowptr);
    hipLaunchKernelGGL(k_fillptr, dim3(gN), blk, 0, stream, packed, bsum, rowptr);
    hipLaunchKernelGGL(k_fill,    dim3(gE), blk, 0, stream, src, dst, ew, dinv, rowptr, ord, csr);

    // layer 0: x W0 -> fp16, then aggregate (no relu, no W epilogue) -> fp16
    hipLaunchKernelGGL(k_gemm0,   dim3(gR4), blk, 0, stream, x, W0, htmp);
    hipLaunchKernelGGL((k_gather2<false, false, false>), dim3(gWF), blk, 0, stream,
                       rowptr, csr, htmp, dinv, (const float*)nullptr, b0, (void*)hA);

    // middle layers 1..6: fused (A relu(h)) W + b, fp16 -> fp16
    __half* hin = hA;
    __half* hout = hB;
    for (int i = 0; i < 6; i++) {
        const float* Wi = Wm + (long)i * 64 * 64;
        const float* bi = bm + (long)i * 64;
        hipLaunchKernelGGL((k_gather2<true, true, false>), dim3(gWF), blk, 0, stream,
                           rowptr, csr, hin, dinv, Wi, bi, (void*)hout);
        __half* t2 = hin; hin = hout; hout = t2;
    }

    // final layer: fused aggregate + W + bias + sigmoid -> fp32 d_out
    hipLaunchKernelGGL((k_gather2<true, true, true>), dim3(gWF), blk, 0, stream,
                       rowptr, csr, hin, dinv, Wl, bl, (void*)out);
}

// Round 6
// 726.559 us; speedup vs baseline: 1.0593x; 1.0593x over previous
//
#include <hip/hip_runtime.h>
#include <hip/hip_fp16.h>
#include <math.h>

#define N_NODES 100000
#define N_EDGES 1600000
#define F_IN 15
#define NB_NODES 391   // ceil(N_NODES/256)
#define MASK40 ((1ull << 40) - 1)

typedef _Float16 half8 __attribute__((ext_vector_type(8)));
typedef float f32x4 __attribute__((ext_vector_type(4)));

// ---------------- prelude ----------------

__global__ void k_initp(unsigned long long* __restrict__ packed) {
    int i = blockIdx.x * blockDim.x + threadIdx.x;
    if (i < N_NODES) packed[i] = 0ull;
}

// one packed 64-bit atomic per edge: count in bits [40..], weight-sum as 32.8
// fixed point below. Returned old count = this edge's CSR ordinal.
__global__ void k_cnt(const int* __restrict__ dst, const float* __restrict__ w,
                      unsigned long long* __restrict__ packed, int* __restrict__ ord) {
    int i = blockIdx.x * blockDim.x + threadIdx.x;
    if (i >= N_EDGES) return;
    int d = dst[i];
    unsigned long long contrib =
        (1ull << 40) + (unsigned long long)((double)w[i] * 4294967296.0);
    unsigned long long old = atomicAdd(&packed[d], contrib);
    ord[i] = (int)(old >> 40);
}

// per-block sum of counts -> bsum; fused dinv = rsqrt(1 + sum_w)
__global__ void k_part(const unsigned long long* __restrict__ packed,
                       int* __restrict__ bsum, float* __restrict__ dinv) {
    __shared__ int red[256];
    int t = threadIdx.x;
    int i = blockIdx.x * 256 + t;
    int c = 0;
    if (i < N_NODES) {
        unsigned long long p = packed[i];
        c = (int)(p >> 40);
        float deg = 1.0f + (float)((double)(p & MASK40) * 0x1p-32);
        dinv[i] = rsqrtf(deg);
    }
    red[t] = c;
    __syncthreads();
    for (int off = 128; off > 0; off >>= 1) {
        if (t < off) red[t] += red[t + off];
        __syncthreads();
    }
    if (t == 0) bsum[blockIdx.x] = red[0];
}

__global__ __launch_bounds__(512) void k_scanb(int* __restrict__ bsum,
                                               int* __restrict__ rowptr) {
    __shared__ int sc[512];
    int t = threadIdx.x;
    int v = (t < NB_NODES) ? bsum[t] : 0;
    sc[t] = v;
    __syncthreads();
    for (int off = 1; off < 512; off <<= 1) {
        int u = (t >= off) ? sc[t - off] : 0;
        __syncthreads();
        sc[t] += u;
        __syncthreads();
    }
    if (t < NB_NODES) bsum[t] = sc[t] - v;
    if (t == 0) rowptr[N_NODES] = N_EDGES;
}

__global__ void k_fillptr(const unsigned long long* __restrict__ packed,
                          const int* __restrict__ bsum, int* __restrict__ rowptr) {
    __shared__ int sc[256];
    int t = threadIdx.x;
    int i = blockIdx.x * 256 + t;
    int v = (i < N_NODES) ? (int)(packed[i] >> 40) : 0;
    sc[t] = v;
    __syncthreads();
    for (int off = 1; off < 256; off <<= 1) {
        int u = (t >= off) ? sc[t - off] : 0;
        __syncthreads();
        sc[t] += u;
        __syncthreads();
    }
    if (i < N_NODES) rowptr[i] = bsum[blockIdx.x] + sc[t] - v;
}

__global__ void k_fill(const int* __restrict__ src, const int* __restrict__ dst,
                       const float* __restrict__ w, const float* __restrict__ dinv,
                       const int* __restrict__ rowptr, const int* __restrict__ ord,
                       int2* __restrict__ csr) {
    int i = blockIdx.x * blockDim.x + threadIdx.x;
    if (i >= N_EDGES) return;
    int s = src[i], d = dst[i];
    float nm = dinv[s] * w[i] * dinv[d];
    csr[rowptr[d] + ord[i]] = make_int2(s, __float_as_int(nm));
}

// ---------------- layer 0 dense transform: [N,15]@[15,64] -> fp16 ----------------

__global__ void k_gemm0(const float* __restrict__ x, const float* __restrict__ W,
                        __half* __restrict__ out) {
    __shared__ float Ws[F_IN * 64];
    int t = threadIdx.x;
    for (int i = t; i < F_IN * 64; i += 256) Ws[i] = W[i];
    __syncthreads();
    int r = blockIdx.x * 4 + (t >> 6);
    int c = t & 63;
    if (r < N_NODES) {
        const float* xr = x + (long)r * F_IN;
        float acc = 0.f;
#pragma unroll
        for (int k = 0; k < F_IN; k++) acc += xr[k] * Ws[k * 64 + c];
        out[(long)r * 64 + c] = __float2half(acc);
    }
}

// ---------------- fused aggregation + MFMA dense epilogue ----------------
// Block = 32 nodes (4 waves x 8). Phase 1: each wave stages its CSR segment
// into LDS (coalesced), then gathers g = A act(h) with unchained h loads.
// Phase 2 (WEP): G[32x64] fp16 in LDS -> O = G @ (W_hi+W_lo) + b via
// mfma_f32_16x16x32_f16 (hi/lo split keeps W at ~fp32 precision).

#define SE_CAP 256          // staged edges per wave (chunked if exceeded)
#define G_STRIDE 72         // halves; 144 B rows keep half8 loads 16B-aligned

template <bool RELU, bool WEP, bool SIG>
__global__ __launch_bounds__(256) void k_gather3(
        const int* __restrict__ rowptr, const int2* __restrict__ csr,
        const __half* __restrict__ hin, const float* __restrict__ dinv,
        const float* __restrict__ W, const float* __restrict__ b,
        void* __restrict__ outp) {
    extern __shared__ char smem[];
    int t = threadIdx.x, wv = t >> 6, lane = t & 63;
    int2* se = (int2*)smem + wv * SE_CAP;                 // 4 x 2 KB
    _Float16* G = (_Float16*)(smem + 4 * SE_CAP * 8);     // [32][G_STRIDE]

    int nb = blockIdx.x * 32;      // block's first node (grid exact: 3125*32=100000)
    int n0w = nb + wv * 8;         // wave's first node

    int rp[9];
#pragma unroll
    for (int j = 0; j < 9; j++) rp[j] = rowptr[n0w + j];  // broadcast loads
    int base = rp[0], end = rp[8];

    // self-loop init: acc[j] = dinv^2 * act(h[n])
    float acc[8];
#pragma unroll
    for (int j = 0; j < 8; j++) {
        int n = n0w + j;
        float dv = dinv[n];
        float h = __half2float(hin[(long)n * 64 + lane]);
        if (RELU) h = fmaxf(h, 0.f);
        acc[j] = dv * dv * h;
    }

    for (int cb = base; cb < end; cb += SE_CAP) {
        int ce = cb + SE_CAP; if (ce > end) ce = end;
        int cn = ce - cb;
        // stage csr chunk: coalesced global -> LDS
        for (int i = lane; i < cn; i += 64) se[i] = csr[cb + i];
        __builtin_amdgcn_wave_barrier();   // DS ops in-order within a wave
#pragma unroll
        for (int j = 0; j < 8; j++) {
            int lo = rp[j] < cb ? cb : rp[j];
            int hi = rp[j + 1] > ce ? ce : rp[j + 1];
            int i = lo - cb, iend = hi - cb;
            for (; i + 7 < iend; i += 8) {
                int2 r0 = se[i],     r1 = se[i + 1], r2 = se[i + 2], r3 = se[i + 3];
                int2 r4 = se[i + 4], r5 = se[i + 5], r6 = se[i + 6], r7 = se[i + 7];
                float h0 = __half2float(hin[(long)r0.x * 64 + lane]);
                float h1 = __half2float(hin[(long)r1.x * 64 + lane]);
                float h2 = __half2float(hin[(long)r2.x * 64 + lane]);
                float h3 = __half2float(hin[(long)r3.x * 64 + lane]);
                float h4 = __half2float(hin[(long)r4.x * 64 + lane]);
                float h5 = __half2float(hin[(long)r5.x * 64 + lane]);
                float h6 = __half2float(hin[(long)r6.x * 64 + lane]);
                float h7 = __half2float(hin[(long)r7.x * 64 + lane]);
                if (RELU) {
                    h0 = fmaxf(h0, 0.f); h1 = fmaxf(h1, 0.f);
                    h2 = fmaxf(h2, 0.f); h3 = fmaxf(h3, 0.f);
                    h4 = fmaxf(h4, 0.f); h5 = fmaxf(h5, 0.f);
                    h6 = fmaxf(h6, 0.f); h7 = fmaxf(h7, 0.f);
                }
                acc[j] += __int_as_float(r0.y) * h0 + __int_as_float(r1.y) * h1
                        + __int_as_float(r2.y) * h2 + __int_as_float(r3.y) * h3
                        + __int_as_float(r4.y) * h4 + __int_as_float(r5.y) * h5
                        + __int_as_float(r6.y) * h6 + __int_as_float(r7.y) * h7;
            }
            for (; i < iend; i++) {
                int2 r = se[i];
                float h = __half2float(hin[(long)r.x * 64 + lane]);
                if (RELU) h = fmaxf(h, 0.f);
                acc[j] += __int_as_float(r.y) * h;
            }
        }
        __builtin_amdgcn_wave_barrier();
    }

    if (!WEP) {
        // layer 0 path: out = g + b, fp16 pre-relu
#pragma unroll
        for (int j = 0; j < 8; j++)
            ((__half*)outp)[(long)(n0w + j) * 64 + lane] = __float2half(acc[j] + b[lane]);
        return;
    }

    // write G rows (fp16)
#pragma unroll
    for (int j = 0; j < 8; j++)
        G[(wv * 8 + j) * G_STRIDE + lane] = (_Float16)acc[j];
    __syncthreads();   // all 32 rows complete

    // ---- MFMA epilogue: O[32x64] = G @ W + b ----
    int col = lane & 15, quad = lane >> 4;
    int mrow = (wv & 1) * 16;        // m-stripe of this wave
    int nc0 = (wv >> 1) * 32;        // n-stripe (2 tiles of 16)

    // A-frags: A[m=col][k=quad*8+j + kt*32], contiguous half8 from G
    half8 af[2];
#pragma unroll
    for (int kt = 0; kt < 2; kt++)
        af[kt] = *(const half8*)&G[(mrow + col) * G_STRIDE + kt * 32 + quad * 8];

    // B-frags from global fp32 W, hi/lo fp16 split: B[k=kt*32+quad*8+j][n]
    half8 bf[2][2][2];  // [nt][kt][hi/lo]
#pragma unroll
    for (int nt = 0; nt < 2; nt++) {
#pragma unroll
        for (int kt = 0; kt < 2; kt++) {
#pragma unroll
            for (int j = 0; j < 8; j++) {
                float w = W[(kt * 32 + quad * 8 + j) * 64 + nc0 + nt * 16 + col];
                _Float16 hi = (_Float16)w;
                bf[nt][kt][0][j] = hi;
                bf[nt][kt][1][j] = (_Float16)(w - (float)hi);
            }
        }
    }

    f32x4 c0, c1;
    {
        float b0v = b[nc0 + col], b1v = b[nc0 + 16 + col];
        c0 = (f32x4){b0v, b0v, b0v, b0v};
        c1 = (f32x4){b1v, b1v, b1v, b1v};
    }
#pragma unroll
    for (int kt = 0; kt < 2; kt++) {
        c0 = __builtin_amdgcn_mfma_f32_16x16x32_f16(af[kt], bf[0][kt][0], c0, 0, 0, 0);
        c0 = __builtin_amdgcn_mfma_f32_16x16x32_f16(af[kt], bf[0][kt][1], c0, 0, 0, 0);
        c1 = __builtin_amdgcn_mfma_f32_16x16x32_f16(af[kt], bf[1][kt][0], c1, 0, 0, 0);
        c1 = __builtin_amdgcn_mfma_f32_16x16x32_f16(af[kt], bf[1][kt][1], c1, 0, 0, 0);
    }

    // C/D: col = lane&15, row = quad*4 + reg (m89-verified, dtype-independent)
#pragma unroll
    for (int nt = 0; nt < 2; nt++) {
        f32x4 c = nt ? c1 : c0;
#pragma unroll
        for (int r = 0; r < 4; r++) {
            long node = nb + mrow + quad * 4 + r;
            int feat = nc0 + nt * 16 + col;
            float o = c[r];
            if (SIG) {
                o = 1.0f / (1.0f + expf(-o));
                ((float*)outp)[node * 64 + feat] = o;
            } else {
                ((__half*)outp)[node * 64 + feat] = __float2half(o);  // pre-relu
            }
        }
    }
}

// ---------------- launch ----------------

extern "C" void kernel_launch(void* const* d_in, const int* in_sizes, int n_in,
                              void* d_out, int out_size, void* d_ws, size_t ws_size,
                              hipStream_t stream) {
    const float* x  = (const float*)d_in[0];
    const int*   ei = (const int*)  d_in[1];
    const float* ew = (const float*)d_in[2];
    const float* W0 = (const float*)d_in[3];
    const float* b0 = (const float*)d_in[4];
    const float* Wm = (const float*)d_in[5];
    const float* bm = (const float*)d_in[6];
    const float* Wl = (const float*)d_in[7];
    const float* bl = (const float*)d_in[8];
    float* out = (float*)d_out;

    const int* src = ei;
    const int* dst = ei + N_EDGES;

    char* ws = (char*)d_ws;
    unsigned long long* packed = (unsigned long long*)(ws + 0);        // 800 KB
    float*  dinv   = (float*)(ws + (1u  << 20));                        // 400 KB
    int*    rowptr = (int*)  (ws + (2u  << 20));                        // 400 KB
    int*    bsum   = (int*)  (ws + (3u  << 20));                        // 2 KB
    int*    ord    = (int*)  (ws + (3u  << 20) + 65536);                // 6.4 MB
    int2*   csr    = (int2*) (ws + (11u << 20));                        // 12.8 MB
    __half* htmp   = (__half*)(ws + (24u << 20));                       // 12.8 MB
    __half* hA     = (__half*)(ws + (50u << 20));                       // 12.8 MB
    __half* hB     = (__half*)(ws + (63u << 20));                       // 12.8 MB

    const int BT = 256;
    dim3 blk(BT);
    int gN  = NB_NODES;                  // 391
    int gE  = (N_EDGES + BT - 1) / BT;   // 6250
    int gR4 = (N_NODES + 3) / 4;         // 25000 (gemm0)
    int gG  = N_NODES / 32;              // 3125 (gather3: 32 nodes/block, exact)

    const size_t smem0 = 4 * SE_CAP * 8;                          // 8 KB (no G)
    const size_t smemW = 4 * SE_CAP * 8 + 32 * G_STRIDE * 2;      // 12.6 KB

    // prelude: packed count+degree, 3-phase scan, atomic-free CSR fill
    hipLaunchKernelGGL(k_initp,   dim3(gN), blk, 0, stream, packed);
    hipLaunchKernelGGL(k_cnt,     dim3(gE), blk, 0, stream, dst, ew, packed, ord);
    hipLaunchKernelGGL(k_part,    dim3(gN), blk, 0, stream, packed, bsum, dinv);
    hipLaunchKernelGGL(k_scanb,   dim3(1), dim3(512), 0, stream, bsum, rowptr);
    hipLaunchKernelGGL(k_fillptr, dim3(gN), blk, 0, stream, packed, bsum, rowptr);
    hipLaunchKernelGGL(k_fill,    dim3(gE), blk, 0, stream, src, dst, ew, dinv, rowptr, ord, csr);

    // layer 0: x W0 -> fp16, then aggregate (no relu, no W epilogue) -> fp16
    hipLaunchKernelGGL(k_gemm0,   dim3(gR4), blk, 0, stream, x, W0, htmp);
    hipLaunchKernelGGL((k_gather3<false, false, false>), dim3(gG), blk, smem0, stream,
                       rowptr, csr, htmp, dinv, (const float*)nullptr, b0, (void*)hA);

    // middle layers 1..6: fused (A relu(h)) W + b via MFMA epilogue, fp16 -> fp16
    __half* hin = hA;
    __half* hout = hB;
    for (int i = 0; i < 6; i++) {
        const float* Wi = Wm + (long)i * 64 * 64;
        const float* bi = bm + (long)i * 64;
        hipLaunchKernelGGL((k_gather3<true, true, false>), dim3(gG), blk, smemW, stream,
                           rowptr, csr, hin, dinv, Wi, bi, (void*)hout);
        __half* t2 = hin; hin = hout; hout = t2;
    }

    // final layer: fused aggregate + W + bias + sigmoid -> fp32 d_out
    hipLaunchKernelGGL((k_gather3<true, true, true>), dim3(gG), blk, smemW, stream,
                       rowptr, csr, hin, dinv, Wl, bl, (void*)out);
}

// Round 7
// 559.181 us; speedup vs baseline: 1.3764x; 1.2993x over previous
//
#include <hip/hip_runtime.h>
#include <hip/hip_fp16.h>
#include <math.h>

#define N_NODES 100000
#define N_EDGES 1600000
#define F_IN 15
#define NB_NODES 391   // ceil(N_NODES/256)
#define MASK40 ((1ull << 40) - 1)

typedef _Float16 half8 __attribute__((ext_vector_type(8)));
typedef float f32x4 __attribute__((ext_vector_type(4)));

// ---------------- prelude ----------------

__global__ void k_initp(unsigned long long* __restrict__ packed8) {
    int i = blockIdx.x * blockDim.x + threadIdx.x;
    if (i < 8 * N_NODES) packed8[i] = 0ull;
}

// 8-way XCD-local replicated histogram: copy = blockIdx&7 (dispatch round-robins
// XCDs). One packed 64-bit atomic per edge: count in [40..], weight-sum 32.8 fx
// below. Returned old count = within-copy CSR ordinal.
__global__ void k_cnt(const int* __restrict__ dst, const float* __restrict__ w,
                      unsigned long long* __restrict__ packed8, int* __restrict__ ord) {
    int i = blockIdx.x * blockDim.x + threadIdx.x;
    if (i >= N_EDGES) return;
    int copy = blockIdx.x & 7;
    int d = dst[i];
    unsigned long long contrib =
        (1ull << 40) + (unsigned long long)((double)w[i] * 4294967296.0);
    unsigned long long old = atomicAdd(&packed8[(size_t)copy * N_NODES + d], contrib);
    ord[i] = (int)(old >> 40);
}

// per-block sum of (8-copy) counts -> bsum; fused dinv = rsqrt(1 + sum_w)
__global__ void k_part(const unsigned long long* __restrict__ packed8,
                       int* __restrict__ bsum, float* __restrict__ dinv) {
    __shared__ int red[256];
    int t = threadIdx.x;
    int i = blockIdx.x * 256 + t;
    int c = 0;
    if (i < N_NODES) {
        unsigned long long wsum = 0;
#pragma unroll
        for (int cp = 0; cp < 8; cp++) {
            unsigned long long p = packed8[(size_t)cp * N_NODES + i];
            c += (int)(p >> 40);
            wsum += (p & MASK40);
        }
        float deg = 1.0f + (float)((double)wsum * 0x1p-32);
        dinv[i] = rsqrtf(deg);
    }
    red[t] = c;
    __syncthreads();
    for (int off = 128; off > 0; off >>= 1) {
        if (t < off) red[t] += red[t + off];
        __syncthreads();
    }
    if (t == 0) bsum[blockIdx.x] = red[0];
}

__global__ __launch_bounds__(512) void k_scanb(int* __restrict__ bsum,
                                               int* __restrict__ rowptr) {
    __shared__ int sc[512];
    int t = threadIdx.x;
    int v = (t < NB_NODES) ? bsum[t] : 0;
    sc[t] = v;
    __syncthreads();
    for (int off = 1; off < 512; off <<= 1) {
        int u = (t >= off) ? sc[t - off] : 0;
        __syncthreads();
        sc[t] += u;
        __syncthreads();
    }
    if (t < NB_NODES) bsum[t] = sc[t] - v;
    if (t == 0) rowptr[N_NODES] = N_EDGES;
}

// in-block exclusive scan of total counts -> rowptr; also per-copy bases rbase[cp][n]
__global__ void k_fillptr(const unsigned long long* __restrict__ packed8,
                          const int* __restrict__ bsum, int* __restrict__ rowptr,
                          int* __restrict__ rbase) {
    __shared__ int sc[256];
    int t = threadIdx.x;
    int i = blockIdx.x * 256 + t;
    int cnts[8];
    int v = 0;
    if (i < N_NODES) {
#pragma unroll
        for (int cp = 0; cp < 8; cp++) {
            cnts[cp] = (int)(packed8[(size_t)cp * N_NODES + i] >> 40);
            v += cnts[cp];
        }
    }
    sc[t] = v;
    __syncthreads();
    for (int off = 1; off < 256; off <<= 1) {
        int u = (t >= off) ? sc[t - off] : 0;
        __syncthreads();
        sc[t] += u;
        __syncthreads();
    }
    if (i < N_NODES) {
        int run = bsum[blockIdx.x] + sc[t] - v;  // exclusive prefix = rowptr
        rowptr[i] = run;
#pragma unroll
        for (int cp = 0; cp < 8; cp++) {
            rbase[(size_t)cp * N_NODES + i] = run;
            run += cnts[cp];
        }
    }
}

// atomic-free CSR fill: slot = rbase[copy][dst] + within-copy ordinal
__global__ void k_fill(const int* __restrict__ src, const int* __restrict__ dst,
                       const float* __restrict__ w, const float* __restrict__ dinv,
                       const int* __restrict__ rbase, const int* __restrict__ ord,
                       int2* __restrict__ csr) {
    int i = blockIdx.x * blockDim.x + threadIdx.x;
    if (i >= N_EDGES) return;
    int copy = (i >> 8) & 7;   // must mirror k_cnt's block->copy map (256 thr/blk)
    int s = src[i], d = dst[i];
    float nm = dinv[s] * w[i] * dinv[d];
    csr[rbase[(size_t)copy * N_NODES + d] + ord[i]] = make_int2(s, __float_as_int(nm));
}

// ---------------- layer 0 dense transform: [N,15]@[15,64] -> fp16 (no relu) ----

__global__ void k_gemm0(const float* __restrict__ x, const float* __restrict__ W,
                        __half* __restrict__ out) {
    __shared__ float Ws[F_IN * 64];
    int t = threadIdx.x;
    for (int i = t; i < F_IN * 64; i += 256) Ws[i] = W[i];
    __syncthreads();
    int r = blockIdx.x * 4 + (t >> 6);
    int c = t & 63;
    if (r < N_NODES) {
        const float* xr = x + (long)r * F_IN;
        float acc = 0.f;
#pragma unroll
        for (int k = 0; k < F_IN; k++) acc += xr[k] * Ws[k * 64 + c];
        out[(long)r * 64 + c] = __float2half(acc);
    }
}

// ---------------- fused aggregation + MFMA dense epilogue ----------------
// Inputs hin are stored POST-activation (relu applied by the producer), so the
// hot loop has no fmax. Wave = 8 nodes; lane = (sub: which edge of a pair) x
// (fl: feature pair). Records staged in LDS (no global->global chain); one
// global_load_dword covers 2 edges. acc is float2/lane, halves combined by
// one shfl_xor(32) pair per node.

#define SE_CAP 256          // staged edges per wave (chunked if exceeded)
#define G_STRIDE 72         // halves; 144 B rows keep half8 loads 16B-aligned

template <bool WEP, bool SIG>
__global__ __launch_bounds__(256) void k_gather4(
        const int* __restrict__ rowptr, const int2* __restrict__ csr,
        const __half* __restrict__ hin, const float* __restrict__ dinv,
        const float* __restrict__ W, const float* __restrict__ b,
        void* __restrict__ outp) {
    extern __shared__ char smem[];
    int t = threadIdx.x, wv = t >> 6, lane = t & 63;
    int sub = lane >> 5, fl = lane & 31;
    int2* se = (int2*)smem + wv * SE_CAP;                 // 4 x 2 KB
    _Float16* G = (_Float16*)(smem + 4 * SE_CAP * 8);     // [32][G_STRIDE]

    int nb = blockIdx.x * 32;      // grid exact: 3125*32 = 100000
    int n0w = nb + wv * 8;

    int rp[9];
#pragma unroll
    for (int j = 0; j < 9; j++) rp[j] = rowptr[n0w + j];
    int base = rp[0], end = rp[8];

    const __half2* h2 = (const __half2*)hin;  // row stride = 32 half2

    // self-loop init: acc[j] = dinv^2 * h (h already activated by producer)
    float2 acc[8];
#pragma unroll
    for (int j = 0; j < 8; j++) {
        int n = n0w + j;
        float dv = dinv[n];
        float2 hf = __half22float2(h2[(long)n * 32 + fl]);
        float w0 = (sub == 0) ? dv * dv : 0.f;
        acc[j].x = w0 * hf.x;
        acc[j].y = w0 * hf.y;
    }

    for (int cb = base; cb < end; cb += SE_CAP) {
        int ce = cb + SE_CAP; if (ce > end) ce = end;
        int cn = ce - cb;
        for (int i = lane; i < cn; i += 64) se[i] = csr[cb + i];
        __builtin_amdgcn_wave_barrier();
#pragma unroll
        for (int j = 0; j < 8; j++) {
            int lo = rp[j] < cb ? cb : rp[j];
            int hi = rp[j + 1] > ce ? ce : rp[j + 1];
            int i = lo - cb, iend = hi - cb;
            // 4 pairs (8 edges) per iteration
            for (; i + 7 < iend; i += 8) {
                int2 r0 = se[i + sub],     r1 = se[i + 2 + sub];
                int2 r2 = se[i + 4 + sub], r3 = se[i + 6 + sub];
                float2 f0 = __half22float2(h2[(long)r0.x * 32 + fl]);
                float2 f1 = __half22float2(h2[(long)r1.x * 32 + fl]);
                float2 f2 = __half22float2(h2[(long)r2.x * 32 + fl]);
                float2 f3 = __half22float2(h2[(long)r3.x * 32 + fl]);
                float n0 = __int_as_float(r0.y), n1 = __int_as_float(r1.y);
                float n2 = __int_as_float(r2.y), n3 = __int_as_float(r3.y);
                acc[j].x += n0 * f0.x; acc[j].y += n0 * f0.y;
                acc[j].x += n1 * f1.x; acc[j].y += n1 * f1.y;
                acc[j].x += n2 * f2.x; acc[j].y += n2 * f2.y;
                acc[j].x += n3 * f3.x; acc[j].y += n3 * f3.y;
            }
            for (; i + 1 < iend; i += 2) {
                int2 r = se[i + sub];
                float2 f = __half22float2(h2[(long)r.x * 32 + fl]);
                float nm = __int_as_float(r.y);
                acc[j].x += nm * f.x; acc[j].y += nm * f.y;
            }
            if (i < iend) {  // odd tail: sub0 only
                int2 r = se[i];
                float2 f = __half22float2(h2[(long)r.x * 32 + fl]);
                float nm = (sub == 0) ? __int_as_float(r.y) : 0.f;
                acc[j].x += nm * f.x; acc[j].y += nm * f.y;
            }
        }
        __builtin_amdgcn_wave_barrier();
    }

    // combine sub-halves: feature pair fl lives in lanes fl and fl+32
#pragma unroll
    for (int j = 0; j < 8; j++) {
        acc[j].x += __shfl_xor(acc[j].x, 32);
        acc[j].y += __shfl_xor(acc[j].y, 32);
    }

    if (!WEP) {
        // layer 0: out = relu(g + b) fp16, written as half2 by sub0 lanes
        float2 bv = ((const float2*)b)[fl];
        if (sub == 0) {
#pragma unroll
            for (int j = 0; j < 8; j++) {
                float ox = fmaxf(acc[j].x + bv.x, 0.f);
                float oy = fmaxf(acc[j].y + bv.y, 0.f);
                ((__half2*)outp)[(long)(n0w + j) * 32 + fl] = __floats2half2_rn(ox, oy);
            }
        }
        return;
    }

    // write G rows (fp16) from sub0 lanes
    if (sub == 0) {
        __half2* G2 = (__half2*)G;
#pragma unroll
        for (int j = 0; j < 8; j++)
            G2[(wv * 8 + j) * (G_STRIDE / 2) + fl] = __floats2half2_rn(acc[j].x, acc[j].y);
    }
    __syncthreads();

    // ---- MFMA epilogue: O[32x64] = G @ (W_hi + W_lo) + b ----
    int col = lane & 15, quad = lane >> 4;
    int mrow = (wv & 1) * 16;
    int nc0 = (wv >> 1) * 32;

    half8 af[2];
#pragma unroll
    for (int kt = 0; kt < 2; kt++)
        af[kt] = *(const half8*)&G[(mrow + col) * G_STRIDE + kt * 32 + quad * 8];

    half8 bf[2][2][2];  // [nt][kt][hi/lo]
#pragma unroll
    for (int nt = 0; nt < 2; nt++) {
#pragma unroll
        for (int kt = 0; kt < 2; kt++) {
#pragma unroll
            for (int j = 0; j < 8; j++) {
                float w = W[(kt * 32 + quad * 8 + j) * 64 + nc0 + nt * 16 + col];
                _Float16 hi = (_Float16)w;
                bf[nt][kt][0][j] = hi;
                bf[nt][kt][1][j] = (_Float16)(w - (float)hi);
            }
        }
    }

    f32x4 c0, c1;
    {
        float b0v = b[nc0 + col], b1v = b[nc0 + 16 + col];
        c0 = (f32x4){b0v, b0v, b0v, b0v};
        c1 = (f32x4){b1v, b1v, b1v, b1v};
    }
#pragma unroll
    for (int kt = 0; kt < 2; kt++) {
        c0 = __builtin_amdgcn_mfma_f32_16x16x32_f16(af[kt], bf[0][kt][0], c0, 0, 0, 0);
        c0 = __builtin_amdgcn_mfma_f32_16x16x32_f16(af[kt], bf[0][kt][1], c0, 0, 0, 0);
        c1 = __builtin_amdgcn_mfma_f32_16x16x32_f16(af[kt], bf[1][kt][0], c1, 0, 0, 0);
        c1 = __builtin_amdgcn_mfma_f32_16x16x32_f16(af[kt], bf[1][kt][1], c1, 0, 0, 0);
    }

    // C/D: col = lane&15, row = quad*4 + reg
#pragma unroll
    for (int nt = 0; nt < 2; nt++) {
        f32x4 c = nt ? c1 : c0;
#pragma unroll
        for (int r = 0; r < 4; r++) {
            long node = nb + mrow + quad * 4 + r;
            int feat = nc0 + nt * 16 + col;
            float o = c[r];
            if (SIG) {
                o = 1.0f / (1.0f + expf(-o));
                ((float*)outp)[node * 64 + feat] = o;
            } else {
                o = fmaxf(o, 0.f);  // relu at producer: store post-activation
                ((__half*)outp)[node * 64 + feat] = __float2half(o);
            }
        }
    }
}

// ---------------- launch ----------------

extern "C" void kernel_launch(void* const* d_in, const int* in_sizes, int n_in,
                              void* d_out, int out_size, void* d_ws, size_t ws_size,
                              hipStream_t stream) {
    const float* x  = (const float*)d_in[0];
    const int*   ei = (const int*)  d_in[1];
    const float* ew = (const float*)d_in[2];
    const float* W0 = (const float*)d_in[3];
    const float* b0 = (const float*)d_in[4];
    const float* Wm = (const float*)d_in[5];
    const float* bm = (const float*)d_in[6];
    const float* Wl = (const float*)d_in[7];
    const float* bl = (const float*)d_in[8];
    float* out = (float*)d_out;

    const int* src = ei;
    const int* dst = ei + N_EDGES;

    char* ws = (char*)d_ws;
    unsigned long long* packed8 = (unsigned long long*)(ws + 0);       // 6.4 MB
    float*  dinv   = (float*)(ws + (7u  << 20));                        // 400 KB
    int*    rowptr = (int*)  (ws + (8u  << 20));                        // 400 KB
    int*    bsum   = (int*)  (ws + (9u  << 20));                        // 2 KB
    int*    ord    = (int*)  (ws + (9u  << 20) + 65536);                // 6.4 MB
    int*    rbase  = (int*)  (ws + (16u << 20));                        // 3.2 MB
    int2*   csr    = (int2*) (ws + (20u << 20));                        // 12.8 MB
    __half* htmp   = (__half*)(ws + (33u << 20));                       // 12.8 MB
    __half* hA     = (__half*)(ws + (46u << 20));                       // 12.8 MB
    __half* hB     = (__half*)(ws + (59u << 20));                       // 12.8 MB

    const int BT = 256;
    dim3 blk(BT);
    int gN  = NB_NODES;                       // 391
    int gN8 = (8 * N_NODES + BT - 1) / BT;    // 3125 (init packed8)
    int gE  = (N_EDGES + BT - 1) / BT;        // 6250
    int gR4 = (N_NODES + 3) / 4;              // 25000 (gemm0)
    int gG  = N_NODES / 32;                   // 3125 (gather4: 32 nodes/block)

    const size_t smem0 = 4 * SE_CAP * 8;                          // 8 KB
    const size_t smemW = 4 * SE_CAP * 8 + 32 * G_STRIDE * 2;      // 12.5 KB

    // prelude: 8-way replicated count+degree, 3-phase scan, atomic-free CSR fill
    hipLaunchKernelGGL(k_initp,   dim3(gN8), blk, 0, stream, packed8);
    hipLaunchKernelGGL(k_cnt,     dim3(gE),  blk, 0, stream, dst, ew, packed8, ord);
    hipLaunchKernelGGL(k_part,    dim3(gN),  blk, 0, stream, packed8, bsum, dinv);
    hipLaunchKernelGGL(k_scanb,   dim3(1), dim3(512), 0, stream, bsum, rowptr);
    hipLaunchKernelGGL(k_fillptr, dim3(gN),  blk, 0, stream, packed8, bsum, rowptr, rbase);
    hipLaunchKernelGGL(k_fill,    dim3(gE),  blk, 0, stream, src, dst, ew, dinv, rbase, ord, csr);

    // layer 0: x W0 -> fp16 (pre-act), then aggregate +b0, relu at store -> hA
    hipLaunchKernelGGL(k_gemm0,   dim3(gR4), blk, 0, stream, x, W0, htmp);
    hipLaunchKernelGGL((k_gather4<false, false>), dim3(gG), blk, smem0, stream,
                       rowptr, csr, htmp, dinv, (const float*)nullptr, b0, (void*)hA);

    // middle layers 1..6: fused (A h) W + b via MFMA, relu at store, fp16 -> fp16
    __half* hin = hA;
    __half* hout = hB;
    for (int i = 0; i < 6; i++) {
        const float* Wi = Wm + (long)i * 64 * 64;
        const float* bi = bm + (long)i * 64;
        hipLaunchKernelGGL((k_gather4<true, false>), dim3(gG), blk, smemW, stream,
                           rowptr, csr, hin, dinv, Wi, bi, (void*)hout);
        __half* t2 = hin; hin = hout; hout = t2;
    }

    // final layer: fused aggregate + W + bias + sigmoid -> fp32 d_out
    hipLaunchKernelGGL((k_gather4<true, true>), dim3(gG), blk, smemW, stream,
                       rowptr, csr, hin, dinv, Wl, bl, (void*)out);
}